// Round 11
// baseline (151.598 us; speedup 1.0000x reference)
//
#include <hip/hip_runtime.h>
#include <math.h>

#define Bsz 120
#define Nv  128
#define Ms  192            // checks per s (rows of Hz for s=0, Hx for s=1)
#define Tit 25
#define DC  16             // max check degree (clip; verified sufficient: absmax 0.0)
#define DV  24             // max var degree   (verified sufficient)
#define EPADW 960          // edge ids < 960 (E~768, +7 sigma); dummy region base
#define SENT  1152         // sentinel zero slot (= EPADW + 192)
#define CNSZ  1153

// ws layout (ints): [0] last-block counter | [2..] float part[2][Bsz][Tit]
#define WS_CNT  0
#define WS_PART 2

// phi(x) = -log(tanh(x/2)) = ln2*(log2(1+u) - log2(1-u)), u = e^-x, clip [1e-6,30].
// Small-x: 1-u by series to kill cancellation. (FROZEN: bit-exact vs reference.)
__device__ __forceinline__ float phi_f(float x) {
  x = fminf(fmaxf(x, 1e-6f), 30.0f);
  const float u = __expf(-x);
  float den = 1.0f - u;
  if (x < 0.03125f) den = x * (1.0f - 0.5f * x + 0.16666667f * x * x);
  return 0.69314718f * (__log2f(1.0f + u) - __log2f(den));
}

#define USH(arr, k) ((arr[(k) >> 1] >> (((k) & 1) * 16)) & 0xffff)

// ---------------------------------------------------------------------------
// Fully fused, TWO-PHASE iteration (BP's minimum communication structure):
//   check phase (thread=check): csum gather -> phi x2 in regs -> cn write
//   var phase   (thread=var):   cn gather -> sigmoid -> csum/corr write
// 2 barriers/iter (was 4). Previous-iter cn in registers (no p/pt2 LDS
// round-trips). Loss deferred: corr history in LDS, butterflies post-loop.
// All per-slot code branch-free: predication via cndmask on values/addresses.
// ---------------------------------------------------------------------------
__global__ __launch_bounds__(256, 1) void nbp_kernel(
    const float* __restrict__ errorx, const float* __restrict__ errorz,
    const float* __restrict__ ep0,
    const float* __restrict__ Hx, const float* __restrict__ Hz,
    const float* __restrict__ Gx, const float* __restrict__ Gz,
    const float* __restrict__ w_llr, const float* __restrict__ w_vn,
    const float* __restrict__ w_cn,
    int* __restrict__ W, float* __restrict__ out) {
  __shared__ unsigned mask_l[Ms][4];         // row bit-masks (build)
  __shared__ int rp_l[Ms + 1];               // CSR offsets (build + cn addressing)
  __shared__ unsigned colmask[Nv][6];        // column bit-masks (build)
  __shared__ unsigned short ncol_l[Ms * DC]; // check -> var ids (pad = Nv)
  __shared__ unsigned short veid_l[Nv * DV]; // var -> edge ids (pad = SENT)
  __shared__ float cn_l[CNSZ];               // cn messages; [960..1151] dummy, [1152]=0
  __shared__ float csum_l[Nv + 1];           // per-var cn sum; [Nv] = 0 sentinel
  __shared__ float corrh[Tit][Nv];           // corr history for deferred loss
  __shared__ float wls[Tit], wvs[Tit], wcs[Tit];
  __shared__ float plost[Tit];
  __shared__ int wtot[3];
  __shared__ float wred[4], wredm[4];
  __shared__ int lastFlag;

  const int tid = threadIdx.x;
  const int lane = tid & 63, wv = tid >> 6;
  const int bid = blockIdx.x;
  const int b = bid >> 1, s = bid & 1;
  float* partBase = (float*)(W + WS_PART);
  float* part = partBase + (s * Bsz + b) * Tit;

  const float ep   = ep0[0];
  const float a23  = (2.0f * ep) / 3.0f;
  const float llr0 = logf((1.0f - a23) / a23);

  // ==== S1: weights; zero colmask/cn; sentinel ncol; esyn stage; row masks ====
  if (tid < Tit) {
    wls[tid] = w_llr[tid];
    wvs[tid] = w_vn[tid];
    wcs[tid] = w_cn[tid];
  }
  {
    unsigned* cmf = &colmask[0][0];
    for (int i = tid; i < Nv * 6; i += 256) cmf[i] = 0;
    unsigned* nc32 = (unsigned*)ncol_l;
    for (int i = tid; i < Ms * DC / 2; i += 256) nc32[i] = (Nv << 16) | Nv;
    for (int i = tid; i < CNSZ; i += 256) cn_l[i] = 0.f;
  }
  if (tid < Nv) {
    const float* esyn = (s ? errorz : errorx) + b * Nv;  // syndrome selector
    csum_l[tid] = esyn[tid];              // temp stage (x0 at t=0: harmless)
  }
  if (tid == 0) csum_l[Nv] = 0.f;
  unsigned mwa[4] = {0, 0, 0, 0};
  int d = 0;
  if (tid < Ms) {
    const float4* H4 = (const float4*)((s ? Hx : Hz) + tid * Nv);  // Hs=[Hz,Hx]
#pragma unroll
    for (int w = 0; w < 4; ++w) {
      unsigned bits = 0;
#pragma unroll
      for (int q = 0; q < 8; ++q) {
        const float4 v = H4[w * 8 + q];
        if (v.x > 0.f) bits |= 1u << (q * 4 + 0);
        if (v.y > 0.f) bits |= 1u << (q * 4 + 1);
        if (v.z > 0.f) bits |= 1u << (q * 4 + 2);
        if (v.w > 0.f) bits |= 1u << (q * 4 + 3);
      }
      mwa[w] = bits;
      mask_l[tid][w] = bits;
      d += __popc(bits);
    }
  }
  const int dgc = (d <= DC) ? d : DC;       // clipped degree
  __syncthreads();

  // ==== S2: shfl prefix scan of degrees -> rp_l ====
  {
    int x = dgc;
#pragma unroll
    for (int off = 1; off < 64; off <<= 1) {
      const int y = __shfl_up(x, off);
      if (lane >= off) x += y;
    }
    if (lane == 63 && wv < 3) wtot[wv] = x;
    __syncthreads();
    int carry = 0;
    for (int k = 0; k < wv && k < 3; ++k) carry += wtot[k];
    if (tid < Ms) {
      const int incl = x + carry;
      rp_l[tid] = incl - dgc;
      if (tid == Ms - 1) rp_l[Ms] = incl;
    }
  }
  __syncthreads();

  // ==== S3: emit ncol (check-local) + column-mask transpose ====
  if (tid < Ms) {
    const unsigned wbit = 1u << (tid & 31);
    const int wrd = tid >> 5;
    int cnt = 0;
#pragma unroll
    for (int w = 0; w < 4; ++w) {
      unsigned bits = mwa[w];
      while (bits) {
        const int j = __ffs(bits) - 1;
        bits &= bits - 1;
        const int n = w * 32 + j;
        if (cnt < DC) ncol_l[tid * DC + cnt] = (unsigned short)n;
        ++cnt;
        atomicOr(&colmask[n][wrd], wbit);
      }
    }
  }
  __syncthreads();

  // ==== S4: register tables; veid build; ssgn; G/ec loads ====
  unsigned ncp[8];
  {
    const uint4* q = (const uint4*)(ncol_l + ((tid < Ms) ? tid : 0) * DC);
    const uint4 a0 = q[0], a1 = q[1];
    ncp[0] = a0.x; ncp[1] = a0.y; ncp[2] = a0.z; ncp[3] = a0.w;
    ncp[4] = a1.x; ncp[5] = a1.y; ncp[6] = a1.z; ncp[7] = a1.w;
  }
  const int rp0 = (tid < Ms) ? rp_l[tid] : 0;
  const int dg0 = (tid < Ms) ? dgc : 0;
  if (tid < Nv) {
    const int wnd = tid >> 5;
    const unsigned lowmask = (1u << (tid & 31)) - 1u;
    int kk = 0;
#pragma unroll
    for (int w6 = 0; w6 < 6; ++w6) {
      unsigned bits = colmask[tid][w6];
      while (bits) {
        const int m2 = w6 * 32 + (__ffs(bits) - 1);
        bits &= bits - 1;
        int r = __popc(mask_l[m2][wnd] & lowmask);
        for (int w = 0; w < wnd; ++w) r += __popc(mask_l[m2][w]);
        if (kk < DV && r < DC) veid_l[tid * DV + kk] = (unsigned short)(rp_l[m2] + r);
        if (r < DC) ++kk;
      }
    }
    for (int z = kk; z < DV; ++z) veid_l[tid * DV + z] = (unsigned short)SENT;
  }
  float ssgn;
  {
    unsigned par = 0;
#pragma unroll
    for (int k = 0; k < DC; ++k) {
      const int nn = USH(ncp, k);
      const float ev = csum_l[nn];        // esyn staged; sentinel -> 0
      par ^= (k < dg0) ? ((ev > 0.5f) ? 1u : 0u) : 0u;
    }
    ssgn = (par & 1u) ? -1.f : 1.f;
  }
  // G rows, per-lane (used by every wave in deferred loss)
  const float* G = s ? Gz : Gx;            // s=0: Gx·corrz ; s=1: Gz·corrx
  const float g0a = G[lane],      g0b = G[lane + 64];
  const float g1a = G[Nv + lane], g1b = G[Nv + lane + 64];
  float ec = 0.f;
  if (tid < Nv) ec = ((s ? errorx : errorz) + b * Nv)[tid];
  unsigned vep[12];
  if (tid < Nv) {
    const uint4* q = (const uint4*)(veid_l + tid * DV);
    const uint4 a0 = q[0], a1 = q[1], a2 = q[2];
    vep[0] = a0.x; vep[1] = a0.y; vep[2]  = a0.z; vep[3]  = a0.w;
    vep[4] = a1.x; vep[5] = a1.y; vep[6]  = a1.z; vep[7]  = a1.w;
    vep[8] = a2.x; vep[9] = a2.y; vep[10] = a2.z; vep[11] = a2.w;
  } else {
#pragma unroll
    for (int i = 0; i < 12; ++i) vep[i] = (SENT << 16) | SENT;
  }
  __syncthreads();

  // ==== main loop: 2 phases, 2 barriers per iteration ====
  float cn_reg[DC];
#pragma unroll
  for (int k = 0; k < DC; ++k) cn_reg[k] = 0.f;
  float basePrev = llr0, wvPrev = 0.f;     // t=0 reconstructs V = llr0 exactly

#pragma unroll 1
  for (int t = 0; t < Tit; ++t) {
    // ---- check phase: thread = check (tid < 192; uniform wave branch) ----
    if (tid < Ms) {
      const float wct = wcs[t];
      float pa[DC];
      float psum = 0.f;
      unsigned par = 0;
#pragma unroll
      for (int k = 0; k < DC; ++k) {
        const int nn = USH(ncp, k);
        const float csv = csum_l[nn];      // sentinel var -> csum_l[Nv] = 0
        const float Vk = basePrev + wvPrev * (csv - cn_reg[k]);
        const float pv = phi_f(fabsf(Vk));
        pa[k] = (Vk < 0.f) ? -pv : pv;
        psum += (k < dg0) ? pv : 0.f;
        par ^= (k < dg0) ? (__float_as_uint(Vk) >> 31) : 0u;
      }
      const float tot = ((par & 1u) ? -ssgn : ssgn) * wct;
#pragma unroll
      for (int k = 0; k < DC; ++k) {
        const float ps = pa[k];
        const float sg = (__float_as_uint(ps) >> 31) ? -1.f : 1.f;
        const float cnk = tot * sg * phi_f(psum - fabsf(ps));
        cn_reg[k] = cnk;
        const int addr = (k < dg0) ? (rp0 + k) : (EPADW + tid);  // branch-free
        cn_l[addr] = cnk;
      }
    }
    __syncthreads();

    // ---- var phase: thread = var (tid < 128; uniform wave branch) ----
    const float base_t = wls[t] * llr0;
    if (tid < Nv) {
      float cs = 0.f;
#pragma unroll
      for (int k = 0; k < DV; ++k) cs += cn_l[USH(vep, k)];
      csum_l[tid] = cs;
      const float prob = 1.0f / (1.0f + __expf(base_t + cs));  // sigmoid(-Gamma)
      corrh[t][tid] = (ec > 0.5f) ? 1.0f - prob : prob;
    }
    basePrev = base_t;
    wvPrev = wvs[t];
    __syncthreads();
  }

  // ==== deferred loss: 25 butterflies spread across the 4 waves ====
#pragma unroll 1
  for (int i = 0; i < 7; ++i) {
    const int t = wv + 4 * i;
    if (t < Tit) {
      const float c0 = corrh[t][lane], c1 = corrh[t][lane + 64];
      float la = g0a * c0 + g0b * c1;
      float lb = g1a * c0 + g1b * c1;
#pragma unroll
      for (int off = 1; off < 64; off <<= 1) {
        la += __shfl_xor(la, off);
        lb += __shfl_xor(lb, off);
      }
      const float lt = fabsf(__sinf(1.57079632679f * la)) +
                       fabsf(__sinf(1.57079632679f * lb));
      if (lane == 0) plost[t] = lt;
    }
  }
  __syncthreads();

  // ---- single global write of this chain's 25 losses ----
  if (tid < Tit) part[tid] = plost[tid];

  // ---- fused final combine: threadfence + atomic counter, last block ----
  __threadfence();
  if (tid == 0) lastFlag = (atomicAdd(W + WS_CNT, 1) == 2 * Bsz - 1);
  __syncthreads();
  if (lastFlag) {
    __threadfence();
    float sm = 0.f, mn = 0.f;
    if (tid < Bsz) {
      const float* pa2 = partBase + tid * Tit;           // s=0
      const float* pb2 = partBase + (Bsz + tid) * Tit;   // s=1
      float acc = 0.f, mloc = 3.0e38f;
#pragma unroll
      for (int t = 0; t < Tit; ++t) {
        const float lt = pa2[t] + pb2[t];
        acc += lt;
        mloc = fminf(mloc, lt);
      }
      sm = acc;
      mn = mloc;
    }
#pragma unroll
    for (int off = 32; off; off >>= 1) {
      sm += __shfl_down(sm, off);
      mn += __shfl_down(mn, off);
    }
    if ((tid & 63) == 0) { wred[tid >> 6] = sm; wredm[tid >> 6] = mn; }
    __syncthreads();
    if (tid == 0) {
      out[0] = (wred[0] + wred[1]) * (1.0f / Bsz);
      out[1] = (wredm[0] + wredm[1]) * (1.0f / Bsz);
    }
  }
}

extern "C" void kernel_launch(void* const* d_in, const int* in_sizes, int n_in,
                              void* d_out, int out_size, void* d_ws, size_t ws_size,
                              hipStream_t stream) {
  const float* errorx = (const float*)d_in[0];
  const float* errorz = (const float*)d_in[1];
  const float* ep0    = (const float*)d_in[2];
  const float* Hx     = (const float*)d_in[3];
  const float* Hz     = (const float*)d_in[4];
  const float* Gx     = (const float*)d_in[5];
  const float* Gz     = (const float*)d_in[6];
  const float* wllr   = (const float*)d_in[7];
  const float* wvn    = (const float*)d_in[8];
  const float* wcn    = (const float*)d_in[9];
  float* out = (float*)d_out;
  int* W = (int*)d_ws;

  hipMemsetAsync((void*)(W + WS_CNT), 0, sizeof(int), stream);  // zero counter
  hipLaunchKernelGGL(nbp_kernel, dim3(2 * Bsz), dim3(256), 0, stream,
                     errorx, errorz, ep0, Hx, Hz, Gx, Gz, wllr, wvn, wcn, W, out);
}